// Round 10
// baseline (117.277 us; speedup 1.0000x reference)
//
#include <hip/hip_runtime.h>

typedef unsigned short u16x8 __attribute__((ext_vector_type(8)));
typedef short          s16x8 __attribute__((ext_vector_type(8)));
typedef float          f32x4 __attribute__((ext_vector_type(4)));

#define NTOK   4096      // B*S
#define DMODEL 1024
#define NEXP   16
#define TOPK   2
#define BK     32
#define KSPLIT 2
#define KHALF  (DMODEL / KSPLIT)       // 512
#define NK2    (KHALF / BK)            // 16 K-steps per block
#define MAXT   128       // 32 shared tiles + <=80 routed tiles (BM=128)

// RNE float->bf16
__device__ inline unsigned short f2bf(float f) {
    unsigned int x = __float_as_uint(f);
    x += 0x7fffu + ((x >> 16) & 1u);
    return (unsigned short)(x >> 16);
}
__device__ inline float bf2f(unsigned short h) {
    unsigned int x = ((unsigned int)h) << 16;
    return __uint_as_float(x);
}

// async global->LDS, 16B/lane; LDS dest wave-uniform base, HW adds lane*16
__device__ inline void gld16(const void* g, void* l) {
    __builtin_amdgcn_global_load_lds(
        (const __attribute__((address_space(1))) void*)g,
        (__attribute__((address_space(3))) void*)l, 16, 0, 0);
}

// ============ fused prep: routing blocks 0..1023 (NO global atomics), conversions after ============
#define NWR8  (NEXP * DMODEL * DMODEL / 8)       // 2097152
#define NWS8  (DMODEL * DMODEL / 8)              // 131072
#define NB8   ((NEXP + 1) * DMODEL / 8)          // 2176
#define RBLK  (NTOK / 4)                         // 1024 routing blocks
#define CBLK  ((NWR8 + NWS8 + NB8 + 255) / 256)  // conversion blocks

__global__ void prep_kernel(const float* __restrict__ u,
                            const float* __restrict__ cent,
                            const float* __restrict__ ebias,
                            const float* __restrict__ Wr,
                            const float* __restrict__ br,
                            const float* __restrict__ Ws,
                            const float* __restrict__ bs,
                            unsigned short* __restrict__ ub,
                            unsigned short* __restrict__ w17,
                            float* __restrict__ b17,
                            float* __restrict__ topk_g,
                            int*   __restrict__ topk_i) {
    int bid = blockIdx.x;
    if (bid >= RBLK) {
        // ---- conversion part (vectorized f32x4 loads) ----
        int id = (bid - RBLK) * 256 + threadIdx.x;
        if (id < NWR8) {
            size_t base = (size_t)id * 8;
            f32x4 a = *(const f32x4*)&Wr[base];
            f32x4 b = *(const f32x4*)&Wr[base + 4];
            u16x8 o;
#pragma unroll
            for (int i = 0; i < 4; i++) { o[i] = f2bf(a[i]); o[i + 4] = f2bf(b[i]); }
            *(u16x8*)&w17[base] = o;
        } else if (id < NWR8 + NWS8) {
            size_t base = (size_t)(id - NWR8) * 8;
            f32x4 a0 = *(const f32x4*)&Ws[base];
            f32x4 b0 = *(const f32x4*)&Ws[base + 4];
            f32x4 a1 = *(const f32x4*)&Ws[(size_t)DMODEL * DMODEL + base];
            f32x4 b1 = *(const f32x4*)&Ws[(size_t)DMODEL * DMODEL + base + 4];
            u16x8 o;
#pragma unroll
            for (int i = 0; i < 4; i++) {
                o[i]     = f2bf(a0[i] + a1[i]);
                o[i + 4] = f2bf(b0[i] + b1[i]);
            }
            *(u16x8*)&w17[(size_t)NEXP * DMODEL * DMODEL + base] = o;
        } else if (id < NWR8 + NWS8 + NB8) {
            int base = (id - NWR8 - NWS8) * 8;
#pragma unroll
            for (int i = 0; i < 8; i++) {
                int idx = base + i;
                b17[idx] = idx < NEXP * DMODEL
                    ? br[idx]
                    : bs[idx - NEXP * DMODEL] + bs[idx - NEXP * DMODEL + DMODEL];
            }
        }
        return;
    }
    // ---- routing part: fp64 scores, softmax, top-2, fused u->bf16 ----
    int wid  = threadIdx.x >> 6;
    int lane = threadIdx.x & 63;
    int t = bid * 4 + wid;
    const float* urow = u + (size_t)t * DMODEL;

    double acc[NEXP];
#pragma unroll
    for (int e = 0; e < NEXP; e++) acc[e] = 0.0;

    for (int j = 0; j < DMODEL / 64; j++) {
        int d = j * 64 + lane;
        float uf = urow[d];
        ub[(size_t)t * DMODEL + d] = f2bf(uf);
        double uv = (double)uf;
#pragma unroll
        for (int e = 0; e < NEXP; e++)
            acc[e] += uv * (double)cent[e * DMODEL + d];
    }
#pragma unroll
    for (int e = 0; e < NEXP; e++) {
        for (int off = 32; off; off >>= 1)
            acc[e] += __shfl_xor(acc[e], off);
    }
    if (lane == 0) {
        double mx = -1e300;
#pragma unroll
        for (int e = 0; e < NEXP; e++) {
            acc[e] += (double)ebias[e];
            if (acc[e] > mx) mx = acc[e];
        }
        double ex[NEXP], den = 0.0;
#pragma unroll
        for (int e = 0; e < NEXP; e++) { ex[e] = exp(acc[e] - mx); den += ex[e]; }
        int i1 = -1, i2 = -1;
        double v1 = -1.0, v2 = -1.0;
        for (int e = 0; e < NEXP; e++) {
            double v = ex[e];
            if (v > v1)      { v2 = v1; i2 = i1; v1 = v; i1 = e; }
            else if (v > v2) { v2 = v;  i2 = e; }
        }
        topk_g[t * 2 + 0] = (float)(v1 / den);
        topk_g[t * 2 + 1] = (float)(v2 / den);
        topk_i[t * 2 + 0] = i1;
        topk_i[t * 2 + 1] = i2;
    }
}

// ------------- single block: bucket pairs via LDS atomics + tile descriptors -------------
__global__ void build_all(const float* __restrict__ topk_g,
                          const int*   __restrict__ topk_i,
                          int* __restrict__ cnt,
                          int* __restrict__ tokL,
                          float* __restrict__ gateL,
                          int* __restrict__ idL,
                          int* __restrict__ desc,
                          int* __restrict__ numT) {
    __shared__ int scnt[NEXP];
    int tid = threadIdx.x;
    if (tid < NEXP) scnt[tid] = 0;
    __syncthreads();
    for (int id = tid; id < NTOK * TOPK; id += 1024) {
        int e = topk_i[id];
        int pos = atomicAdd(&scnt[e], 1);
        tokL[e * NTOK + pos]  = id >> 1;
        gateL[e * NTOK + pos] = topk_g[id];
        idL[e * NTOK + pos]   = id;
    }
    __syncthreads();
    if (tid == 0) {
        int s = 0;
        for (int mt = 0; mt < NTOK / 128; mt++) desc[s++] = (NEXP << 16) | mt; // shared
        for (int e = 0; e < NEXP; e++) {
            cnt[e] = scnt[e];
            int nt = (scnt[e] + 127) >> 7;
            for (int m = 0; m < nt; m++) desc[s++] = (e << 16) | m;
        }
        numT[0] = s;
    }
}

// ============ merged MoE GEMM: 128x128, BK=32, split-K=2, R6 schedule ============
// 4 waves (2x2), per-wave 64x64 (acc[4][4]); 2-buffer, 2 barriers/step, vmcnt(4).
// LDS 32KB -> up to 4 blocks/CU (launch_bounds cap). Swizzle: R6-verified, 0 conflicts.
// ks=0 computes K[0,512): writes out/y0 WITH bias (+u for shared).
// ks=1 computes K[512,1024): writes raw partials so1/y1 (bf16).
__global__ __launch_bounds__(256, 4)
void moe_gemm(const unsigned short* __restrict__ ub,   // [4096][1024] bf16
              const unsigned short* __restrict__ w17,  // [17][1024][1024] bf16 (B^T)
              const float* __restrict__ b17,           // [17][1024]
              const int*   __restrict__ cnt,
              const int*   __restrict__ tokL,
              const float* __restrict__ gateL,
              const int*   __restrict__ idL,
              const int*   __restrict__ desc,
              const int*   __restrict__ numT,
              const float* __restrict__ u,
              float* __restrict__ out,
              unsigned short* __restrict__ y,          // [2][8192][1024] bf16
              unsigned short* __restrict__ so1) {      // [4096][1024] bf16
    int bid = blockIdx.x;
    int n0   = (bid & 7) * 128;       // n-panel fastest -> XCD-pinned weight slice
    int tk   = bid >> 3;
    int tile = tk >> 1;
    int ks   = tk & 1;
    if (tile >= numT[0]) return;
    int d = desc[tile];
    int e = d >> 16;
    int row0 = (d & 0xffff) << 7;
    bool is_shared = (e == NEXP);
    int count = is_shared ? NTOK : cnt[e];
    int kbase = ks * KHALF;

    __shared__ __align__(16) unsigned short As[2][128 * BK];
    __shared__ __align__(16) unsigned short Bs[2][128 * BK];

    int t = threadIdx.x;
    int lane = t & 63, wid = t >> 6;
    int wm = wid >> 1, wn = wid & 1;
    int lr = lane & 15, lk4 = lane >> 4;
    int rchunk = (lk4 ^ ((lr >> 1) & 3)) * 8;        // swizzled read chunk (elems)

    int srow = lane >> 2;                            // 0..15 row within 16-row group
    int scs  = ((lane & 3) ^ ((lane >> 3) & 3)) * 8; // inverse-swizzled source chunk

    const int* tl = tokL + e * NTOK;
    const unsigned short* asrc[2];
    const unsigned short* bsrc[2];
    const unsigned short* bb = w17 + (size_t)e * DMODEL * DMODEL + (size_t)n0 * DMODEL;
#pragma unroll
    for (int p = 0; p < 2; p++) {
        int gi = row0 + wid * 32 + p * 16 + srow;
        int tok = is_shared ? gi : tl[gi < count ? gi : count - 1];
        asrc[p] = ub + (size_t)tok * DMODEL + kbase + scs;
        bsrc[p] = bb + (size_t)(wid * 32 + p * 16 + srow) * DMODEL + kbase + scs;
    }

#define STAGE(buf, kt) do {                                                     \
    int _k0 = (kt) * BK;                                                        \
    _Pragma("unroll")                                                           \
    for (int p = 0; p < 2; p++) {                                               \
        int r = wid * 32 + p * 16;                                              \
        gld16(asrc[p] + _k0, &As[buf][r * BK]);                                 \
        gld16(bsrc[p] + _k0, &Bs[buf][r * BK]);                                 \
    } } while (0)

    f32x4 acc[4][4];
#pragma unroll
    for (int i = 0; i < 4; i++)
#pragma unroll
        for (int j = 0; j < 4; j++)
#pragma unroll
            for (int v = 0; v < 4; v++) acc[i][j][v] = 0.0f;

    STAGE(0, 0);
    int cur = 0;
    for (int kt = 0; kt < NK2; kt++) {
        if (kt + 1 < NK2) {
            STAGE(cur ^ 1, kt + 1);                          // 8 outstanding
            asm volatile("s_waitcnt vmcnt(4)" ::: "memory"); // kt's 4 landed
        } else {
            asm volatile("s_waitcnt vmcnt(0)" ::: "memory");
        }
        __builtin_amdgcn_s_barrier();

        __builtin_amdgcn_s_setprio(1);
        s16x8 b[4];
#pragma unroll
        for (int j = 0; j < 4; j++)
            b[j] = *(const s16x8*)&Bs[cur][(wn * 64 + j * 16 + lr) * BK + rchunk];
#pragma unroll
        for (int i = 0; i < 4; i++) {
            s16x8 a = *(const s16x8*)&As[cur][(wm * 64 + i * 16 + lr) * BK + rchunk];
#pragma unroll
            for (int j = 0; j < 4; j++)
                acc[i][j] = __builtin_amdgcn_mfma_f32_16x16x32_bf16(a, b[j], acc[i][j], 0, 0, 0);
        }
        __builtin_amdgcn_s_setprio(0);

        asm volatile("" ::: "memory");               // keep ds_reads above barrier
        __builtin_amdgcn_s_barrier();
        cur ^= 1;
    }
#undef STAGE

    const float* be = b17 + e * DMODEL;
    if (is_shared) {
        if (ks == 0) {
#pragma unroll
            for (int i = 0; i < 4; i++)
#pragma unroll
                for (int v = 0; v < 4; v++) {
                    int row = row0 + wm * 64 + i * 16 + lk4 * 4 + v;
#pragma unroll
                    for (int j = 0; j < 4; j++) {
                        int col = n0 + wn * 64 + j * 16 + lr;
                        size_t idx = (size_t)row * DMODEL + col;
                        out[idx] = u[idx] + 0.5f * (acc[i][j][v] + be[col]);
                    }
                }
        } else {
#pragma unroll
            for (int i = 0; i < 4; i++)
#pragma unroll
                for (int v = 0; v < 4; v++) {
                    int row = row0 + wm * 64 + i * 16 + lk4 * 4 + v;
#pragma unroll
                    for (int j = 0; j < 4; j++) {
                        int col = n0 + wn * 64 + j * 16 + lr;
                        so1[(size_t)row * DMODEL + col] = f2bf(acc[i][j][v]);
                    }
                }
        }
    } else {
        unsigned short* yk = y + (size_t)ks * NTOK * TOPK * DMODEL;
#pragma unroll
        for (int i = 0; i < 4; i++)
#pragma unroll
            for (int v = 0; v < 4; v++) {
                int gi = row0 + wm * 64 + i * 16 + lk4 * 4 + v;
                if (gi < count) {
                    int id = idL[e * NTOK + gi];
                    float g = gateL[e * NTOK + gi];
                    unsigned short* yr = yk + (size_t)id * DMODEL;
#pragma unroll
                    for (int j = 0; j < 4; j++) {
                        int col = n0 + wn * 64 + j * 16 + lr;
                        float val = (ks == 0) ? g * (acc[i][j][v] + be[col])
                                              : g * acc[i][j][v];
                        yr[col] = f2bf(val);
                    }
                }
            }
    }
}

// out[t] += 0.5*so1[t] + y0[2t]+y1[2t] + y0[2t+1]+y1[2t+1]
__global__ void combine_kernel(const unsigned short* __restrict__ y,
                               const unsigned short* __restrict__ so1,
                               float* __restrict__ out) {
    int idx = blockIdx.x * 256 + threadIdx.x;      // NTOK*DMODEL/8 threads
    int tk = idx >> 7;                             // 128 chunks of 8 per token
    int d8 = (idx & 127) * 8;
    size_t base = (size_t)tk * DMODEL + d8;
    const unsigned short* y1 = y + (size_t)NTOK * TOPK * DMODEL;
    u16x8 a0 = *(const u16x8*)&y [(size_t)(tk * 2) * DMODEL + d8];
    u16x8 a1 = *(const u16x8*)&y1[(size_t)(tk * 2) * DMODEL + d8];
    u16x8 b0 = *(const u16x8*)&y [(size_t)(tk * 2 + 1) * DMODEL + d8];
    u16x8 b1 = *(const u16x8*)&y1[(size_t)(tk * 2 + 1) * DMODEL + d8];
    u16x8 s1 = *(const u16x8*)&so1[base];
    f32x4 o0 = *(const f32x4*)&out[base];
    f32x4 o1 = *(const f32x4*)&out[base + 4];
#pragma unroll
    for (int v = 0; v < 4; v++) {
        o0[v] += 0.5f * bf2f(s1[v]) + bf2f(a0[v]) + bf2f(a1[v]) + bf2f(b0[v]) + bf2f(b1[v]);
        o1[v] += 0.5f * bf2f(s1[v + 4]) + bf2f(a0[v + 4]) + bf2f(a1[v + 4])
               + bf2f(b0[v + 4]) + bf2f(b1[v + 4]);
    }
    *(f32x4*)&out[base] = o0;
    *(f32x4*)&out[base + 4] = o1;
}

extern "C" void kernel_launch(void* const* d_in, const int* in_sizes, int n_in,
                              void* d_out, int out_size, void* d_ws, size_t ws_size,
                              hipStream_t stream) {
    const float* u    = (const float*)d_in[0];
    const float* cent = (const float*)d_in[1];
    const float* eb   = (const float*)d_in[2];
    const float* Wr   = (const float*)d_in[3];
    const float* br   = (const float*)d_in[4];
    const float* Ws   = (const float*)d_in[5];
    const float* bs   = (const float*)d_in[6];
    float* out = (float*)d_out;

    char* ws = (char*)d_ws;
    size_t off = 0;
    auto take = [&](size_t b) { size_t o = off; off += (b + 255) & ~(size_t)255; return o; };
    float* topk_g = (float*)(ws + take(NTOK * TOPK * 4));
    int*   topk_i = (int*)  (ws + take(NTOK * TOPK * 4));
    int*   cnt    = (int*)  (ws + take(64 * 4));
    int*   tokL   = (int*)  (ws + take((size_t)NEXP * NTOK * 4));
    float* gateL  = (float*)(ws + take((size_t)NEXP * NTOK * 4));
    int*   idL    = (int*)  (ws + take((size_t)NEXP * NTOK * 4));
    int*   desc   = (int*)  (ws + take(MAXT * 4));
    int*   numT   = (int*)  (ws + take(64));
    float* b17    = (float*)(ws + take((size_t)(NEXP + 1) * DMODEL * 4));
    unsigned short* ub  = (unsigned short*)(ws + take((size_t)NTOK * DMODEL * 2));
    unsigned short* w17 = (unsigned short*)(ws + take((size_t)(NEXP + 1) * DMODEL * DMODEL * 2));
    unsigned short* y   = (unsigned short*)(ws + take((size_t)KSPLIT * NTOK * TOPK * DMODEL * 2));
    unsigned short* so1 = (unsigned short*)(ws + take((size_t)NTOK * DMODEL * 2));

    prep_kernel<<<RBLK + CBLK, 256, 0, stream>>>(
        u, cent, eb, Wr, br, Ws, bs, ub, w17, b17, topk_g, topk_i);
    build_all<<<1, 1024, 0, stream>>>(topk_g, topk_i, cnt, tokL, gateL, idL, desc, numT);
    moe_gemm<<<8 * 2 * MAXT, 256, 0, stream>>>(
        ub, w17, b17, cnt, tokL, gateL, idL, desc, numT, u, out, y, so1);
    combine_kernel<<<(NTOK * DMODEL / 8) / 256, 256, 0, stream>>>(y, so1, out);
}

// Round 11
// 100.005 us; speedup vs baseline: 1.1727x; 1.1727x over previous
//
#include <hip/hip_runtime.h>

typedef unsigned short u16x8 __attribute__((ext_vector_type(8)));
typedef short          s16x8 __attribute__((ext_vector_type(8)));
typedef float          f32x4 __attribute__((ext_vector_type(4)));

#define NTOK   4096      // B*S
#define DMODEL 1024
#define NEXP   16
#define TOPK   2
#define BK     32
#define NK     (DMODEL / BK)   // 32 K-steps
#define MAXT   128       // 32 shared tiles + <=80 routed tiles (BM=128)

// RNE float->bf16
__device__ inline unsigned short f2bf(float f) {
    unsigned int x = __float_as_uint(f);
    x += 0x7fffu + ((x >> 16) & 1u);
    return (unsigned short)(x >> 16);
}
__device__ inline float bf2f(unsigned short h) {
    unsigned int x = ((unsigned int)h) << 16;
    return __uint_as_float(x);
}

// async global->LDS, 16B/lane; LDS dest wave-uniform base, HW adds lane*16
__device__ inline void gld16(const void* g, void* l) {
    __builtin_amdgcn_global_load_lds(
        (const __attribute__((address_space(1))) void*)g,
        (__attribute__((address_space(3))) void*)l, 16, 0, 0);
}

// ============ fused prep: routing blocks 0..1023 (NO global atomics), conversions after ============
#define NWR8  (NEXP * DMODEL * DMODEL / 8)       // 2097152
#define NWS8  (DMODEL * DMODEL / 8)              // 131072
#define NB8   ((NEXP + 1) * DMODEL / 8)          // 2176
#define RBLK  (NTOK / 4)                         // 1024 routing blocks
#define CBLK  ((NWR8 + NWS8 + NB8 + 255) / 256)  // conversion blocks

__global__ void prep_kernel(const float* __restrict__ u,
                            const float* __restrict__ cent,
                            const float* __restrict__ ebias,
                            const float* __restrict__ Wr,
                            const float* __restrict__ br,
                            const float* __restrict__ Ws,
                            const float* __restrict__ bs,
                            unsigned short* __restrict__ ub,
                            unsigned short* __restrict__ w17,
                            float* __restrict__ b17,
                            float* __restrict__ topk_g,
                            int*   __restrict__ topk_i) {
    int bid = blockIdx.x;
    if (bid >= RBLK) {
        // ---- conversion part (vectorized f32x4 loads) ----
        int id = (bid - RBLK) * 256 + threadIdx.x;
        if (id < NWR8) {
            size_t base = (size_t)id * 8;
            f32x4 a = *(const f32x4*)&Wr[base];
            f32x4 b = *(const f32x4*)&Wr[base + 4];
            u16x8 o;
#pragma unroll
            for (int i = 0; i < 4; i++) { o[i] = f2bf(a[i]); o[i + 4] = f2bf(b[i]); }
            *(u16x8*)&w17[base] = o;
        } else if (id < NWR8 + NWS8) {
            size_t base = (size_t)(id - NWR8) * 8;
            f32x4 a0 = *(const f32x4*)&Ws[base];
            f32x4 b0 = *(const f32x4*)&Ws[base + 4];
            f32x4 a1 = *(const f32x4*)&Ws[(size_t)DMODEL * DMODEL + base];
            f32x4 b1 = *(const f32x4*)&Ws[(size_t)DMODEL * DMODEL + base + 4];
            u16x8 o;
#pragma unroll
            for (int i = 0; i < 4; i++) {
                o[i]     = f2bf(a0[i] + a1[i]);
                o[i + 4] = f2bf(b0[i] + b1[i]);
            }
            *(u16x8*)&w17[(size_t)NEXP * DMODEL * DMODEL + base] = o;
        } else if (id < NWR8 + NWS8 + NB8) {
            int base = (id - NWR8 - NWS8) * 8;
#pragma unroll
            for (int i = 0; i < 8; i++) {
                int idx = base + i;
                b17[idx] = idx < NEXP * DMODEL
                    ? br[idx]
                    : bs[idx - NEXP * DMODEL] + bs[idx - NEXP * DMODEL + DMODEL];
            }
        }
        return;
    }
    // ---- routing part: fp64 scores, softmax, top-2, fused u->bf16 ----
    int wid  = threadIdx.x >> 6;
    int lane = threadIdx.x & 63;
    int t = bid * 4 + wid;
    const float* urow = u + (size_t)t * DMODEL;

    double acc[NEXP];
#pragma unroll
    for (int e = 0; e < NEXP; e++) acc[e] = 0.0;

    for (int j = 0; j < DMODEL / 64; j++) {
        int d = j * 64 + lane;
        float uf = urow[d];
        ub[(size_t)t * DMODEL + d] = f2bf(uf);
        double uv = (double)uf;
#pragma unroll
        for (int e = 0; e < NEXP; e++)
            acc[e] += uv * (double)cent[e * DMODEL + d];
    }
#pragma unroll
    for (int e = 0; e < NEXP; e++) {
        for (int off = 32; off; off >>= 1)
            acc[e] += __shfl_xor(acc[e], off);
    }
    if (lane == 0) {
        double mx = -1e300;
#pragma unroll
        for (int e = 0; e < NEXP; e++) {
            acc[e] += (double)ebias[e];
            if (acc[e] > mx) mx = acc[e];
        }
        double ex[NEXP], den = 0.0;
#pragma unroll
        for (int e = 0; e < NEXP; e++) { ex[e] = exp(acc[e] - mx); den += ex[e]; }
        int i1 = -1, i2 = -1;
        double v1 = -1.0, v2 = -1.0;
        for (int e = 0; e < NEXP; e++) {
            double v = ex[e];
            if (v > v1)      { v2 = v1; i2 = i1; v1 = v; i1 = e; }
            else if (v > v2) { v2 = v;  i2 = e; }
        }
        topk_g[t * 2 + 0] = (float)(v1 / den);
        topk_g[t * 2 + 1] = (float)(v2 / den);
        topk_i[t * 2 + 0] = i1;
        topk_i[t * 2 + 1] = i2;
    }
}

// ------------- single block: bucket pairs via LDS atomics + tile descriptors -------------
__global__ void build_all(const float* __restrict__ topk_g,
                          const int*   __restrict__ topk_i,
                          int* __restrict__ cnt,
                          int* __restrict__ tokL,
                          float* __restrict__ gateL,
                          int* __restrict__ idL,
                          int* __restrict__ desc,
                          int* __restrict__ numT) {
    __shared__ int scnt[NEXP];
    int tid = threadIdx.x;
    if (tid < NEXP) scnt[tid] = 0;
    __syncthreads();
    for (int id = tid; id < NTOK * TOPK; id += 1024) {
        int e = topk_i[id];
        int pos = atomicAdd(&scnt[e], 1);
        tokL[e * NTOK + pos]  = id >> 1;
        gateL[e * NTOK + pos] = topk_g[id];
        idL[e * NTOK + pos]   = id;
    }
    __syncthreads();
    if (tid == 0) {
        int s = 0;
        for (int mt = 0; mt < NTOK / 128; mt++) desc[s++] = (NEXP << 16) | mt; // shared
        for (int e = 0; e < NEXP; e++) {
            cnt[e] = scnt[e];
            int nt = (scnt[e] + 127) >> 7;
            for (int m = 0; m < nt; m++) desc[s++] = (e << 16) | m;
        }
        numT[0] = s;
    }
}

// ============ merged MoE GEMM: R6 champion structure (verbatim schedule) ============
// 128x128 tile, BK=32, 4 waves (2x2), per-wave 64x64 (acc[4][4]).
// 2-buffer, 2 barriers/K-step, counted vmcnt(4). LDS 32KB -> 4 blocks/CU.
// XOR swizzle (verified 0 conflicts): chunk c ^= (row>>1)&3 within 64B rows;
// linear gld16 dest + inverse-swizzled global source + swizzled ds_read.
__global__ __launch_bounds__(256, 4)
void moe_gemm(const unsigned short* __restrict__ ub,   // [4096][1024] bf16
              const unsigned short* __restrict__ w17,  // [17][1024][1024] bf16 (B^T)
              const float* __restrict__ b17,           // [17][1024]
              const int*   __restrict__ cnt,
              const int*   __restrict__ tokL,
              const float* __restrict__ gateL,
              const int*   __restrict__ idL,
              const int*   __restrict__ desc,
              const int*   __restrict__ numT,
              const float* __restrict__ u,
              float* __restrict__ out,
              unsigned short* __restrict__ y) {        // [8192][1024] bf16
    int bid = blockIdx.x;
    int tile = bid >> 3;              // n fastest -> XCD = bid%8 = n-panel
    int n0 = (bid & 7) * 128;
    if (tile >= numT[0]) return;
    int d = desc[tile];
    int e = d >> 16;
    int row0 = (d & 0xffff) << 7;
    bool is_shared = (e == NEXP);
    int count = is_shared ? NTOK : cnt[e];

    __shared__ __align__(16) unsigned short As[2][128 * BK];
    __shared__ __align__(16) unsigned short Bs[2][128 * BK];

    int t = threadIdx.x;
    int lane = t & 63, wid = t >> 6;
    int wm = wid >> 1, wn = wid & 1;
    int lr = lane & 15, lk4 = lane >> 4;
    int rchunk = (lk4 ^ ((lr >> 1) & 3)) * 8;        // swizzled read chunk (elems)

    int srow = lane >> 2;                            // 0..15 row within 16-row group
    int scs  = ((lane & 3) ^ ((lane >> 3) & 3)) * 8; // inverse-swizzled source chunk

    const int* tl = tokL + e * NTOK;
    const unsigned short* asrc[2];
    const unsigned short* bsrc[2];
    const unsigned short* bb = w17 + (size_t)e * DMODEL * DMODEL + (size_t)n0 * DMODEL;
#pragma unroll
    for (int p = 0; p < 2; p++) {
        int gi = row0 + wid * 32 + p * 16 + srow;
        int tok = is_shared ? gi : tl[gi < count ? gi : count - 1];
        asrc[p] = ub + (size_t)tok * DMODEL + scs;
        bsrc[p] = bb + (size_t)(wid * 32 + p * 16 + srow) * DMODEL + scs;
    }

#define STAGE(buf, kt) do {                                                     \
    int _k0 = (kt) * BK;                                                        \
    _Pragma("unroll")                                                           \
    for (int p = 0; p < 2; p++) {                                               \
        int r = wid * 32 + p * 16;                                              \
        gld16(asrc[p] + _k0, &As[buf][r * BK]);                                 \
        gld16(bsrc[p] + _k0, &Bs[buf][r * BK]);                                 \
    } } while (0)

    f32x4 acc[4][4];
#pragma unroll
    for (int i = 0; i < 4; i++)
#pragma unroll
        for (int j = 0; j < 4; j++)
#pragma unroll
            for (int v = 0; v < 4; v++) acc[i][j][v] = 0.0f;

    STAGE(0, 0);
    int cur = 0;
    for (int kt = 0; kt < NK; kt++) {
        if (kt + 1 < NK) {
            STAGE(cur ^ 1, kt + 1);                          // 8 outstanding
            asm volatile("s_waitcnt vmcnt(4)" ::: "memory"); // kt's 4 landed
        } else {
            asm volatile("s_waitcnt vmcnt(0)" ::: "memory");
        }
        __builtin_amdgcn_s_barrier();

        __builtin_amdgcn_s_setprio(1);
        s16x8 b[4];
#pragma unroll
        for (int j = 0; j < 4; j++)
            b[j] = *(const s16x8*)&Bs[cur][(wn * 64 + j * 16 + lr) * BK + rchunk];
#pragma unroll
        for (int i = 0; i < 4; i++) {
            s16x8 a = *(const s16x8*)&As[cur][(wm * 64 + i * 16 + lr) * BK + rchunk];
#pragma unroll
            for (int j = 0; j < 4; j++)
                acc[i][j] = __builtin_amdgcn_mfma_f32_16x16x32_bf16(a, b[j], acc[i][j], 0, 0, 0);
        }
        __builtin_amdgcn_s_setprio(0);

        asm volatile("" ::: "memory");               // keep ds_reads above barrier
        __builtin_amdgcn_s_barrier();
        cur ^= 1;
    }
#undef STAGE

    const float* be = b17 + e * DMODEL;
    if (is_shared) {
#pragma unroll
        for (int i = 0; i < 4; i++) {
#pragma unroll
            for (int v = 0; v < 4; v++) {
                int row = row0 + wm * 64 + i * 16 + lk4 * 4 + v;
#pragma unroll
                for (int j = 0; j < 4; j++) {
                    int col = n0 + wn * 64 + j * 16 + lr;
                    size_t idx = (size_t)row * DMODEL + col;
                    out[idx] = u[idx] + 0.5f * (acc[i][j][v] + be[col]);
                }
            }
        }
    } else {
#pragma unroll
        for (int i = 0; i < 4; i++) {
#pragma unroll
            for (int v = 0; v < 4; v++) {
                int gi = row0 + wm * 64 + i * 16 + lk4 * 4 + v;
                if (gi < count) {
                    int id = idL[e * NTOK + gi];
                    float g = gateL[e * NTOK + gi];
                    unsigned short* yr = y + (size_t)id * DMODEL;
#pragma unroll
                    for (int j = 0; j < 4; j++) {
                        int col = n0 + wn * 64 + j * 16 + lr;
                        yr[col] = f2bf(g * (acc[i][j][v] + be[col]));
                    }
                }
            }
        }
    }
}

// out[t] += y[2t] + y[2t+1]   (y bf16)
__global__ void combine_kernel(const unsigned short* __restrict__ y,
                               float* __restrict__ out) {
    int idx = blockIdx.x * 256 + threadIdx.x;      // NTOK*DMODEL/8 threads
    int tk = idx >> 7;                             // 128 chunks of 8 per token
    int d8 = (idx & 127) * 8;
    size_t base = (size_t)tk * DMODEL + d8;
    u16x8 a = *(const u16x8*)&y[(size_t)(tk * 2) * DMODEL + d8];
    u16x8 b = *(const u16x8*)&y[(size_t)(tk * 2 + 1) * DMODEL + d8];
    f32x4 o0 = *(const f32x4*)&out[base];
    f32x4 o1 = *(const f32x4*)&out[base + 4];
#pragma unroll
    for (int v = 0; v < 4; v++) {
        o0[v] += bf2f(a[v]) + bf2f(b[v]);
        o1[v] += bf2f(a[v + 4]) + bf2f(b[v + 4]);
    }
    *(f32x4*)&out[base] = o0;
    *(f32x4*)&out[base + 4] = o1;
}

extern "C" void kernel_launch(void* const* d_in, const int* in_sizes, int n_in,
                              void* d_out, int out_size, void* d_ws, size_t ws_size,
                              hipStream_t stream) {
    const float* u    = (const float*)d_in[0];
    const float* cent = (const float*)d_in[1];
    const float* eb   = (const float*)d_in[2];
    const float* Wr   = (const float*)d_in[3];
    const float* br   = (const float*)d_in[4];
    const float* Ws   = (const float*)d_in[5];
    const float* bs   = (const float*)d_in[6];
    float* out = (float*)d_out;

    char* ws = (char*)d_ws;
    size_t off = 0;
    auto take = [&](size_t b) { size_t o = off; off += (b + 255) & ~(size_t)255; return o; };
    float* topk_g = (float*)(ws + take(NTOK * TOPK * 4));
    int*   topk_i = (int*)  (ws + take(NTOK * TOPK * 4));
    int*   cnt    = (int*)  (ws + take(64 * 4));
    int*   tokL   = (int*)  (ws + take((size_t)NEXP * NTOK * 4));
    float* gateL  = (float*)(ws + take((size_t)NEXP * NTOK * 4));
    int*   idL    = (int*)  (ws + take((size_t)NEXP * NTOK * 4));
    int*   desc   = (int*)  (ws + take(MAXT * 4));
    int*   numT   = (int*)  (ws + take(64));
    float* b17    = (float*)(ws + take((size_t)(NEXP + 1) * DMODEL * 4));
    unsigned short* ub  = (unsigned short*)(ws + take((size_t)NTOK * DMODEL * 2));
    unsigned short* w17 = (unsigned short*)(ws + take((size_t)(NEXP + 1) * DMODEL * DMODEL * 2));
    unsigned short* y   = (unsigned short*)(ws + take((size_t)NTOK * TOPK * DMODEL * 2));

    prep_kernel<<<RBLK + CBLK, 256, 0, stream>>>(
        u, cent, eb, Wr, br, Ws, bs, ub, w17, b17, topk_g, topk_i);
    build_all<<<1, 1024, 0, stream>>>(topk_g, topk_i, cnt, tokL, gateL, idL, desc, numT);
    moe_gemm<<<8 * MAXT, 256, 0, stream>>>(
        ub, w17, b17, cnt, tokL, gateL, idL, desc, numT, u, out, y);
    combine_kernel<<<(NTOK * DMODEL / 8) / 256, 256, 0, stream>>>(y, out);
}